// Round 10
// baseline (1724.218 us; speedup 1.0000x reference)
//
#include <hip/hip_runtime.h>

// 2-layer LSTM (H=128) + FC, round 10: SINGLE-PASS, ALL WEIGHTS RESIDENT.
//
// Key insight: the 128-VGPR cap observed in r1-r9 applies to 512/1024-thread
// blocks; m97-style kernels with smaller blocks get need-based grants >128.
// With 256 threads (4 waves), LDS > 80 KB (1 block/CU) and waves_per_eu(1,1),
// the per-lane budget is 512 VGPRs: all THREE weight matrices fit as
// stationary MFMA B-fragments (3 x 32 frags x 4 VGPR = 384). One loop:
//   iter s: af1 = h1[s-1] tile, af2 = h2[s-2] tile (fragment-order LDS,
//   conflict-free b128). L0: 32 MFMA (whh0) -> pointwise -> h1[s].
//   L1 (lag 1): 32 MFMA (wih1, af1) + 32 MFMA (whh1, af2) -> h2[s-1].
// No h1 global round-trip, no frag reloads, no per-step vmcnt drains
// (x fully preloaded to LDS). 1 barrier/step.
// Tile maps (HW-verified layouts): wave w owns hidden [32w,32w+32);
// nt = e*4+g -> gate g, hidden j = 32w+16e+m16. M-replication: A row m =
// batch row m&3 => acc[nt][reg] = (batch row reg, gate g, hidden j);
// pointwise lane picks reg=kg => all 4 gates in-lane, no redistribution.

#define SEQ  512
#define HID  128
#define NTHR 256
#define NBLK 256

typedef _Float16 half_t;
typedef __attribute__((ext_vector_type(2))) _Float16 half2_t;
typedef __attribute__((ext_vector_type(8))) _Float16 half8_t;
typedef __attribute__((ext_vector_type(4))) float floatx4;

__device__ __forceinline__ half2_t pkrtz(float a, float b) {
    return __builtin_bit_cast(half2_t, __builtin_amdgcn_cvt_pkrtz(a, b));
}
__device__ __forceinline__ float dot2f(half2_t a, half2_t b, float c) {
    return __builtin_amdgcn_fdot2(a, b, c, false);
}
__device__ __forceinline__ float sigm(float v) { return 1.0f / (1.0f + __expf(-v)); }
__device__ __forceinline__ float tanh_fast(float v) {
    float e = __expf(2.0f * v);
    return 1.0f - 2.0f / (e + 1.0f);
}
__device__ __forceinline__ float selr(floatx4 v, int r) {
    float a = (r & 1) ? v[1] : v[0];
    float b = (r & 1) ? v[3] : v[2];
    return (r & 2) ? b : a;
}

__global__ void __launch_bounds__(NTHR, 1)
__attribute__((amdgpu_waves_per_eu(1, 1)))
lstm2_onepass(const float* __restrict__ x,
              const float* __restrict__ w_ih0, const float* __restrict__ w_hh0,
              const float* __restrict__ b_ih0, const float* __restrict__ b_hh0,
              const float* __restrict__ w_ih1, const float* __restrict__ w_hh1,
              const float* __restrict__ b_ih1, const float* __restrict__ b_hh1,
              const float* __restrict__ fc_w,  const float* __restrict__ fc_b,
              float* __restrict__ out)
{
    const int t   = threadIdx.x;
    const int w   = t >> 6;            // wave id: owns hidden [32w, 32w+32)
    const int l   = t & 63;
    const int m16 = l & 15;
    const int kg  = l >> 4;            // frag k-group; pointwise batch row
    const int row0 = blockIdx.x * 4;

    __shared__ __align__(16) float  xs[SEQ][4][8];       // 64 KB, fp32 x
    __shared__ __align__(16) half_t h1t[2][4][64][8];    // fragment-order tiles
    __shared__ __align__(16) half_t h2t[2][4][64][8];
    __shared__ float wpart[4][4];
    __shared__ float ldspad[2048];                       // total ~89 KB > 80 KB

    // ---- preload x into LDS (one-time; removes all per-step global ops) ----
    for (int i = t; i < SEQ * 20; i += NTHR) {
        int s = i / 20, rem = i % 20, r = rem / 5, d = rem % 5;
        xs[s][r][d] = x[(size_t)(row0 + r) * (SEQ * 5) + s * 5 + d];
    }
    for (int i = t; i < 2 * 4 * 64 * 8; i += NTHR) {
        ((half_t*)h1t)[i] = (half_t)0;
        ((half_t*)h2t)[i] = (half_t)0;
    }
    if (t == 0) ldspad[0] = 0.0f;      // keep the occupancy pad alive

    // ---- stationary B-fragments: 3 matrices x 32 frags = 384 VGPRs ----
    half8_t w0f[32], w1f[32], w2f[32];
#pragma unroll
    for (int nt = 0; nt < 8; ++nt) {
#pragma unroll
        for (int kt = 0; kt < 4; ++kt) {
            const size_t grow = (size_t)((nt & 3) * HID + (w << 5) + ((nt >> 2) << 4) + m16);
            const size_t off  = grow * HID + kt * 32 + kg * 8;
            {
                float4 a = *(const float4*)(w_hh0 + off);
                float4 b = *(const float4*)(w_hh0 + off + 4);
                half8_t v;
                v[0]=(half_t)a.x; v[1]=(half_t)a.y; v[2]=(half_t)a.z; v[3]=(half_t)a.w;
                v[4]=(half_t)b.x; v[5]=(half_t)b.y; v[6]=(half_t)b.z; v[7]=(half_t)b.w;
                w0f[nt * 4 + kt] = v;
            }
            {
                float4 a = *(const float4*)(w_ih1 + off);
                float4 b = *(const float4*)(w_ih1 + off + 4);
                half8_t v;
                v[0]=(half_t)a.x; v[1]=(half_t)a.y; v[2]=(half_t)a.z; v[3]=(half_t)a.w;
                v[4]=(half_t)b.x; v[5]=(half_t)b.y; v[6]=(half_t)b.z; v[7]=(half_t)b.w;
                w1f[nt * 4 + kt] = v;
            }
            {
                float4 a = *(const float4*)(w_hh1 + off);
                float4 b = *(const float4*)(w_hh1 + off + 4);
                half8_t v;
                v[0]=(half_t)a.x; v[1]=(half_t)a.y; v[2]=(half_t)a.z; v[3]=(half_t)a.w;
                v[4]=(half_t)b.x; v[5]=(half_t)b.y; v[6]=(half_t)b.z; v[7]=(half_t)b.w;
                w2f[nt * 4 + kt] = v;
            }
        }
    }
    float bias0[8], bias1[8];
    half2_t wxh[8][3];                 // layer-0 x weights, packed fp16
#pragma unroll
    for (int nt = 0; nt < 8; ++nt) {
        int grow = (nt & 3) * HID + (w << 5) + ((nt >> 2) << 4) + m16;
        bias0[nt] = b_ih0[grow] + b_hh0[grow];
        bias1[nt] = b_ih1[grow] + b_hh1[grow];
        const float* p = w_ih0 + grow * 5;
        wxh[nt][0] = pkrtz(p[0], p[1]);
        wxh[nt][1] = pkrtz(p[2], p[3]);
        wxh[nt][2] = pkrtz(p[4], 0.0f);
    }

    float c1a = 0.f, c1b = 0.f, c2a = 0.f, c2b = 0.f, h2a = 0.f, h2b = 0.f;
    const int jsl0 = (m16 >> 3) & 3;           // e=0 slot
    const int jsl1 = (2 + (m16 >> 3)) & 3;     // e=1 slot
    const int je   = m16 & 7;
    __syncthreads();

#pragma unroll 1
    for (int s = 0; s <= SEQ; ++s) {
        const int pb = s & 1, nb = pb ^ 1;
        half8_t af1[4], af2[4];
#pragma unroll
        for (int kt = 0; kt < 4; ++kt) {
            af1[kt] = *(const half8_t*)&h1t[pb][kt][l][0];   // contiguous 1KB/wave
            af2[kt] = *(const half8_t*)&h2t[pb][kt][l][0];
        }

        if (s < SEQ) {   // ---- layer 0, step s ----
            floatx4 a0[8];
#pragma unroll
            for (int nt = 0; nt < 8; ++nt)
                a0[nt] = (floatx4){bias0[nt], bias0[nt], bias0[nt], bias0[nt]};
#pragma unroll
            for (int nt = 0; nt < 8; ++nt)
#pragma unroll
                for (int kt = 0; kt < 4; ++kt)
                    a0[nt] = __builtin_amdgcn_mfma_f32_16x16x32_f16(af1[kt], w0f[nt*4+kt], a0[nt], 0, 0, 0);
            const float* xr = &xs[s][kg][0];
            half2_t x01 = pkrtz(xr[0], xr[1]);
            half2_t x23 = pkrtz(xr[2], xr[3]);
            half2_t x4z = pkrtz(xr[4], 0.0f);
#pragma unroll
            for (int e = 0; e < 2; ++e) {
                float g4[4];
#pragma unroll
                for (int g = 0; g < 4; ++g) {
                    int nt = e * 4 + g;
                    g4[g] = selr(a0[nt], kg) +
                            dot2f(x4z, wxh[nt][2], dot2f(x23, wxh[nt][1], dot2f(x01, wxh[nt][0], 0.f)));
                }
                float iv = sigm(g4[0]), fv = sigm(g4[1]);
                float gv = tanh_fast(g4[2]), ov = sigm(g4[3]);
                float& cc = e ? c1b : c1a;
                cc = fmaf(fv, cc, iv * gv);
                half_t hh = (half_t)(ov * tanh_fast(cc));
                int lane_ = kg + 16 * (e ? jsl1 : jsl0);
#pragma unroll
                for (int a2 = 0; a2 < 4; ++a2) h1t[nb][w][lane_ + 4 * a2][je] = hh;
            }
        }

        if (s > 0) {     // ---- layer 1, step s-1 (af1 = h1[s-1], af2 = h2[s-2]) ----
            floatx4 a1[8];
#pragma unroll
            for (int nt = 0; nt < 8; ++nt)
                a1[nt] = (floatx4){bias1[nt], bias1[nt], bias1[nt], bias1[nt]};
#pragma unroll
            for (int nt = 0; nt < 8; ++nt)
#pragma unroll
                for (int kt = 0; kt < 4; ++kt)
                    a1[nt] = __builtin_amdgcn_mfma_f32_16x16x32_f16(af1[kt], w1f[nt*4+kt], a1[nt], 0, 0, 0);
#pragma unroll
            for (int nt = 0; nt < 8; ++nt)
#pragma unroll
                for (int kt = 0; kt < 4; ++kt)
                    a1[nt] = __builtin_amdgcn_mfma_f32_16x16x32_f16(af2[kt], w2f[nt*4+kt], a1[nt], 0, 0, 0);
#pragma unroll
            for (int e = 0; e < 2; ++e) {
                float gi = selr(a1[e*4+0], kg);
                float gf = selr(a1[e*4+1], kg);
                float gg = selr(a1[e*4+2], kg);
                float go = selr(a1[e*4+3], kg);
                float iv = sigm(gi), fv = sigm(gf), gv = tanh_fast(gg), ov = sigm(go);
                float& cc = e ? c2b : c2a;
                cc = fmaf(fv, cc, iv * gv);
                float hv = ov * tanh_fast(cc);
                if (e) h2b = hv; else h2a = hv;
                half_t hh = (half_t)hv;
                int lane_ = kg + 16 * (e ? jsl1 : jsl0);
#pragma unroll
                for (int a2 = 0; a2 < 4; ++a2) h2t[nb][w][lane_ + 4 * a2][je] = hh;
            }
        }
        __syncthreads();
    }

    // ---- epilogue: out[row] = fc_b + sum_j fc_w[j] * h2[511][row][j] ----
    const int j1 = (w << 5) | m16;
    float p = fc_w[j1] * h2a + fc_w[j1 + 16] * h2b;   // lane = (row kg, hiddens j1, j1+16)
    p += __shfl_xor(p, 1);
    p += __shfl_xor(p, 2);
    p += __shfl_xor(p, 4);
    p += __shfl_xor(p, 8);
    if (m16 == 0) wpart[w][kg] = p;
    __syncthreads();
    if (t < 4) {
        float ssum = fc_b[0];
#pragma unroll
        for (int wv = 0; wv < 4; ++wv) ssum += wpart[wv][t];
        out[row0 + t] = ssum;
    }
}

extern "C" void kernel_launch(void* const* d_in, const int* in_sizes, int n_in,
                              void* d_out, int out_size, void* d_ws, size_t ws_size,
                              hipStream_t stream) {
    (void)in_sizes; (void)n_in; (void)d_ws; (void)ws_size; (void)out_size;
    const float* x     = (const float*)d_in[0];
    const float* w_ih0 = (const float*)d_in[1];
    const float* w_hh0 = (const float*)d_in[2];
    const float* b_ih0 = (const float*)d_in[3];
    const float* b_hh0 = (const float*)d_in[4];
    const float* w_ih1 = (const float*)d_in[5];
    const float* w_hh1 = (const float*)d_in[6];
    const float* b_ih1 = (const float*)d_in[7];
    const float* b_hh1 = (const float*)d_in[8];
    const float* fc_w  = (const float*)d_in[9];
    const float* fc_b  = (const float*)d_in[10];
    float* out = (float*)d_out;

    lstm2_onepass<<<NBLK, NTHR, 0, stream>>>(x, w_ih0, w_hh0, b_ih0, b_hh0,
                                             w_ih1, w_hh1, b_ih1, b_hh1,
                                             fc_w, fc_b, out);
}

// Round 11
// 1276.474 us; speedup vs baseline: 1.3508x; 1.3508x over previous
//
#include <hip/hip_runtime.h>

// 2-layer LSTM (H=128) + FC, round 11: r9 skeleton + measured-overhead fixes.
//
// r10 lesson: MFMA kernels cap at 256 arch VGPRs (AGPR split); 1 wave/SIMD
// exposes all latency. r9 (512 thr, 64-VGPR weight sets, need-based grant
// 108, no spill) is the right skeleton; its overheads were (a) per-step
// vmcnt drains (x load + h1g store before every barrier), (b) phase B's
// unpipelined global h1 reads, (c) h-tile bank conflicts.
// Fixes: x preloaded once into LDS (packed half2); h1 staged in LDS and
// flushed to d_ws as coalesced dwordx4 every 8 steps; phase B 1-deep
// register prefetch; fragment-order h tiles (b128 reads conflict-free).
// xs2+stage alias the phase-BC xgbuf region (disjoint lifetimes).

#define SEQ    512
#define HID    128
#define NTHR   512
#define NBLK   256
#define CHUNK  16
#define NCHUNK (SEQ / CHUNK)

typedef _Float16 half_t;
typedef __attribute__((ext_vector_type(2))) _Float16 half2_t;
typedef __attribute__((ext_vector_type(8))) _Float16 half8_t;
typedef __attribute__((ext_vector_type(4))) float floatx4;

__device__ __forceinline__ half2_t pkrtz(float a, float b) {
    return __builtin_bit_cast(half2_t, __builtin_amdgcn_cvt_pkrtz(a, b));
}
__device__ __forceinline__ float dot2f(half2_t a, half2_t b, float c) {
    return __builtin_amdgcn_fdot2(a, b, c, false);
}
__device__ __forceinline__ float sigm(float v) { return 1.0f / (1.0f + __expf(-v)); }
__device__ __forceinline__ float tanh_fast(float v) {
    float e = __expf(2.0f * v);
    return 1.0f - 2.0f / (e + 1.0f);
}
__device__ __forceinline__ float selr(floatx4 v, int r) {
    float a = (r & 1) ? v[1] : v[0];
    float b = (r & 1) ? v[3] : v[2];
    return (r & 2) ? b : a;
}

__global__ void __launch_bounds__(NTHR)
lstm2_v11(const float* __restrict__ x,
          const float* __restrict__ w_ih0, const float* __restrict__ w_hh0,
          const float* __restrict__ b_ih0, const float* __restrict__ b_hh0,
          const float* __restrict__ w_ih1, const float* __restrict__ w_hh1,
          const float* __restrict__ b_ih1, const float* __restrict__ b_hh1,
          const float* __restrict__ fc_w,  const float* __restrict__ fc_b,
          half_t* __restrict__ h1g, float* __restrict__ out)
{
    const int t   = threadIdx.x;
    const int w   = t >> 6;
    const int l   = t & 63;
    const int m16 = l & 15;
    const int kg  = l >> 4;            // frag k-group; pointwise batch row
    const int jj  = (w << 4) | m16;    // hidden index 0..127
    const int rr  = m16 & 3;           // replicated batch row (B-phase reads)
    const int row0 = blockIdx.x * 4;

    __shared__ __align__(16) floatx4 xgbuf[CHUNK][8][4][16];   // 128 KB (BC)
    __shared__ __align__(16) half_t h1t[2][4][64][8];          // frag-order tiles
    __shared__ __align__(16) half_t h2t[2][4][64][8];
    __shared__ float wpart[8][4];

    // phase-A aliases inside xgbuf (disjoint lifetime):
    half2_t* xs2   = (half2_t*)&xgbuf[0][0][0][0];             // [512][4][3] = 24 KB
    half_t*  stage = (half_t*)(((char*)&xgbuf[0][0][0][0]) + 24576);  // [2][8][512] = 16 KB

    const size_t hbase = (size_t)blockIdx.x * (SEQ * 512);

    half8_t bf[4][4];                  // stationary B-frags: 64 VGPRs
    auto load_frags = [&](const float* W) {
#pragma unroll
        for (int kt = 0; kt < 4; ++kt)
#pragma unroll
            for (int nt = 0; nt < 4; ++nt) {
                const float* p = W + (size_t)(nt * HID + jj) * HID + kt * 32 + kg * 8;
                float4 a = *(const float4*)p;
                float4 b = *(const float4*)(p + 4);
                half8_t v;
                v[0]=(half_t)a.x; v[1]=(half_t)a.y; v[2]=(half_t)a.z; v[3]=(half_t)a.w;
                v[4]=(half_t)b.x; v[5]=(half_t)b.y; v[6]=(half_t)b.z; v[7]=(half_t)b.w;
                bf[kt][nt] = v;
            }
    };

    float bias0v[4], bias1v[4];
#pragma unroll
    for (int nt = 0; nt < 4; ++nt) {
        int g = nt * HID + jj;
        bias0v[nt] = b_ih0[g] + b_hh0[g];
        bias1v[nt] = b_ih1[g] + b_hh1[g];
    }
    half2_t wxh[4][3];                 // layer-0 x weights, packed fp16
#pragma unroll
    for (int nt = 0; nt < 4; ++nt) {
        const float* p = w_ih0 + (nt * HID + jj) * 5;
        wxh[nt][0] = pkrtz(p[0], p[1]);
        wxh[nt][1] = pkrtz(p[2], p[3]);
        wxh[nt][2] = pkrtz(p[4], 0.0f);
    }

    // ---- one-time preloads ----
    for (int i = t; i < SEQ * 4; i += NTHR) {          // x -> packed half2 LDS
        int s = i >> 2, r = i & 3;
        const float* p = x + (size_t)(row0 + r) * (SEQ * 5) + s * 5;
        half2_t* d = xs2 + (size_t)i * 3;
        d[0] = pkrtz(p[0], p[1]);
        d[1] = pkrtz(p[2], p[3]);
        d[2] = pkrtz(p[4], 0.0f);
    }
    for (int i = t; i < 4096; i += NTHR) {
        ((half_t*)h1t)[i] = (half_t)0;
        ((half_t*)h2t)[i] = (half_t)0;
    }
    load_frags(w_hh0);
    float c1 = 0.0f;
    // tile-write coordinates for element (row kg, hidden jj):
    const int kts  = jj >> 5;
    const int slot = (jj >> 3) & 3;
    const int je   = jj & 7;
    __syncthreads();

    // ================= PHASE A: layer 0 =================
#pragma unroll 2
    for (int s = 0; s < SEQ; ++s) {
        const int pb = s & 1, nb = pb ^ 1;
        half8_t af[4];
#pragma unroll
        for (int kt = 0; kt < 4; ++kt)
            af[kt] = *(const half8_t*)&h1t[pb][kt][l][0];   // 64x16B contiguous
        floatx4 acc[4];
#pragma unroll
        for (int nt = 0; nt < 4; ++nt)
            acc[nt] = (floatx4){bias0v[nt], bias0v[nt], bias0v[nt], bias0v[nt]};
#pragma unroll
        for (int kt = 0; kt < 4; ++kt)
#pragma unroll
            for (int nt = 0; nt < 4; ++nt)
                acc[nt] = __builtin_amdgcn_mfma_f32_16x16x32_f16(af[kt], bf[kt][nt], acc[nt], 0, 0, 0);
        {   // pointwise: (row kg, hidden jj)
            const half2_t* xr = xs2 + (size_t)(s * 4 + kg) * 3;
            half2_t x01 = xr[0], x23 = xr[1], x4z = xr[2];
            float gi = selr(acc[0], kg) + dot2f(x4z, wxh[0][2], dot2f(x23, wxh[0][1], dot2f(x01, wxh[0][0], 0.f)));
            float gf = selr(acc[1], kg) + dot2f(x4z, wxh[1][2], dot2f(x23, wxh[1][1], dot2f(x01, wxh[1][0], 0.f)));
            float gg = selr(acc[2], kg) + dot2f(x4z, wxh[2][2], dot2f(x23, wxh[2][1], dot2f(x01, wxh[2][0], 0.f)));
            float go = selr(acc[3], kg) + dot2f(x4z, wxh[3][2], dot2f(x23, wxh[3][1], dot2f(x01, wxh[3][0], 0.f)));
            float iv = sigm(gi), fv = sigm(gf), gv = tanh_fast(gg), ov = sigm(go);
            c1 = fmaf(fv, c1, iv * gv);
            half_t hh = (half_t)(ov * tanh_fast(c1));
#pragma unroll
            for (int a2 = 0; a2 < 4; ++a2)
                h1t[nb][kts][slot * 16 + kg + 4 * a2][je] = hh;   // M-replication
            stage[((s >> 3) & 1) * 4096 + (s & 7) * 512 + kg * HID + jj] = hh;
        }
        __syncthreads();
        if ((s & 7) == 7) {   // coalesced flush: 16 B/thread per 8 steps
            half8_t v = *(const half8_t*)(stage + ((s >> 3) & 1) * 4096 + t * 8);
            *(half8_t*)(h1g + hbase + (size_t)(s - 7) * 512 + t * 8) = v;
        }
    }

    __threadfence();
    __syncthreads();

    // ================= PHASE B/C: layer 1, CHUNK=16 =================
    float c2 = 0.0f, h2v = 0.0f;
    for (int ch = 0; ch < NCHUNK; ++ch) {
        const int s0 = ch * CHUNK;
        // ---- B: xg1 = bias1 + wih1 . h1[s], 1-deep global prefetch ----
        load_frags(w_ih1);
        half8_t pf[4];
#pragma unroll
        for (int kt = 0; kt < 4; ++kt)
            pf[kt] = *(const half8_t*)(h1g + hbase + (size_t)s0 * 512 + rr * HID + kt * 32 + kg * 8);
#pragma unroll 1
        for (int q = 0; q < CHUNK; ++q) {
            half8_t afq[4];
#pragma unroll
            for (int kt = 0; kt < 4; ++kt) afq[kt] = pf[kt];
            if (q + 1 < CHUNK) {
#pragma unroll
                for (int kt = 0; kt < 4; ++kt)
                    pf[kt] = *(const half8_t*)(h1g + hbase + (size_t)(s0 + q + 1) * 512 + rr * HID + kt * 32 + kg * 8);
            }
            floatx4 acc[4];
#pragma unroll
            for (int nt = 0; nt < 4; ++nt)
                acc[nt] = (floatx4){bias1v[nt], bias1v[nt], bias1v[nt], bias1v[nt]};
#pragma unroll
            for (int kt = 0; kt < 4; ++kt)
#pragma unroll
                for (int nt = 0; nt < 4; ++nt)
                    acc[nt] = __builtin_amdgcn_mfma_f32_16x16x32_f16(afq[kt], bf[kt][nt], acc[nt], 0, 0, 0);
            if (l < 16) {
#pragma unroll
                for (int nt = 0; nt < 4; ++nt) xgbuf[q][w][nt][m16] = acc[nt];
            }
        }
        // ---- C: recurrence (1 barrier/step) ----
        load_frags(w_hh1);
#pragma unroll 2
        for (int q = 0; q < CHUNK; ++q) {
            const int s = s0 + q;
            const int pb = s & 1, nb = pb ^ 1;
            half8_t af[4];
#pragma unroll
            for (int kt = 0; kt < 4; ++kt)
                af[kt] = *(const half8_t*)&h2t[pb][kt][l][0];
            floatx4 acc[4];
#pragma unroll
            for (int nt = 0; nt < 4; ++nt)
                acc[nt] = xgbuf[q][w][nt][m16];      // 4-way broadcast, incl bias
#pragma unroll
            for (int kt = 0; kt < 4; ++kt)
#pragma unroll
                for (int nt = 0; nt < 4; ++nt)
                    acc[nt] = __builtin_amdgcn_mfma_f32_16x16x32_f16(af[kt], bf[kt][nt], acc[nt], 0, 0, 0);
            {
                float gi = selr(acc[0], kg);
                float gf = selr(acc[1], kg);
                float gg = selr(acc[2], kg);
                float go = selr(acc[3], kg);
                float iv = sigm(gi), fv = sigm(gf), gv = tanh_fast(gg), ov = sigm(go);
                c2 = fmaf(fv, c2, iv * gv);
                h2v = ov * tanh_fast(c2);
                half_t hh = (half_t)h2v;
#pragma unroll
                for (int a2 = 0; a2 < 4; ++a2)
                    h2t[nb][kts][slot * 16 + kg + 4 * a2][je] = hh;
            }
            __syncthreads();
        }
    }

    // ---- epilogue: out[row] = fc_b + sum_j fc_w[j] * h2[511][row][j] ----
    float p = fc_w[jj] * h2v;                        // lane = (row kg, col jj)
    p += __shfl_xor(p, 1);
    p += __shfl_xor(p, 2);
    p += __shfl_xor(p, 4);
    p += __shfl_xor(p, 8);
    if (m16 == 0) wpart[w][kg] = p;
    __syncthreads();
    if (t < 4) {
        float ssum = fc_b[0];
#pragma unroll
        for (int wv = 0; wv < 8; ++wv) ssum += wpart[wv][t];
        out[row0 + t] = ssum;
    }
}

extern "C" void kernel_launch(void* const* d_in, const int* in_sizes, int n_in,
                              void* d_out, int out_size, void* d_ws, size_t ws_size,
                              hipStream_t stream) {
    (void)in_sizes; (void)n_in; (void)ws_size; (void)out_size;
    const float* x     = (const float*)d_in[0];
    const float* w_ih0 = (const float*)d_in[1];
    const float* w_hh0 = (const float*)d_in[2];
    const float* b_ih0 = (const float*)d_in[3];
    const float* b_hh0 = (const float*)d_in[4];
    const float* w_ih1 = (const float*)d_in[5];
    const float* w_hh1 = (const float*)d_in[6];
    const float* b_ih1 = (const float*)d_in[7];
    const float* b_hh1 = (const float*)d_in[8];
    const float* fc_w  = (const float*)d_in[9];
    const float* fc_b  = (const float*)d_in[10];
    float* out = (float*)d_out;
    half_t* h1g = (half_t*)d_ws;   // 128 MB (validated r6-r9)

    lstm2_v11<<<NBLK, NTHR, 0, stream>>>(x, w_ih0, w_hh0, b_ih0, b_hh0,
                                         w_ih1, w_hh1, b_ih1, b_hh1,
                                         fc_w, fc_b, h1g, out);
}